// Round 2
// baseline (137.728 us; speedup 1.0000x reference)
//
#include <hip/hip_runtime.h>
#include <hip/hip_bf16.h>

// QuIP#-style quantized linear. R12: coalesce the qidxs index stream.
// Model (6 structural nulls: occupancy x2.2, pipeline depth x4, L1/sc0/mixed
// paths, KSPLIT): qgemm is walled by a uniform per-CU vmem request rate
// (~2.3-3.4cy/lane-request, shared upstream of the L1/bypass split). The
// 8.4M random 16B codebook gathers are irreducible; the qidxs loads
// (16B/lane at 4KB stride = 32-64 requests/instr, 20-33% of the stream)
// are NOT. R12 stages each wave's 32 index rows through LDS with fully
// coalesced 64B-line loads (16 req/instr), reads iv from LDS bank-swizzled.
// Requests/CU: ~41-49K -> ~35K. To stay <=64KB static LDS, xt is a 512-k
// half-tile (32KB) restaged once at g==16; qidx staging = 32KB (2KB/wave,
// 2-buf chunks of 4 groups, self-paced per wave, no extra barriers).
// Gather pipeline/MFMA order identical to R11 champion -> absmax identical.

typedef __attribute__((ext_vector_type(16))) float f32x16;
typedef __attribute__((ext_vector_type(8))) __bf16 bf16x8;
typedef __attribute__((ext_vector_type(4))) __bf16 bf16x4;
typedef __attribute__((ext_vector_type(4))) int i32x4;

#define IN_F 8192
#define OUT_F 8192
#define TOKENS 32
#define KSPLIT 8
#define KCHUNK 1024                // k per block
#define XTK 512                    // k per xt half-tile
#define CH (XTK / 8)               // 64 16B-chunks per token row in LDS
#define GROUPS (KCHUNK / 32)       // 32 pipeline groups (4 codes each)
#define DG 5                       // gather lookahead (groups)
#define DI 7                       // idx lookahead (groups)
#define INV_SQRT_8192 0.011048543456039806f
#define PAD(i) ((i) + ((i) >> 5))

#if __has_builtin(__builtin_amdgcn_raw_buffer_load_b128) && \
    __has_builtin(__builtin_amdgcn_make_buffer_rsrc)
#define HAVE_BUF 1
#else
#define HAVE_BUF 0
#endif

// ---------------- register FWHT-32 ----------------
__device__ inline void fwht32_reg(float* r) {
    #pragma unroll
    for (int h = 1; h < 32; h <<= 1)
        #pragma unroll
        for (int i = 0; i < 32; i += 2 * h)
            #pragma unroll
            for (int j = 0; j < h; ++j) {
                float a = r[i + j], b = r[i + j + h];
                r[i + j] = a + b;
                r[i + j + h] = a - b;
            }
}

// ---------------- full FWHT-8192 in padded LDS, 256 threads ----------------
__device__ inline void fwht8192_lds(float* s, int tid) {
    float r[32];
    int b1 = tid * 32;                       // pass 1: bits 0-4
    #pragma unroll
    for (int j = 0; j < 32; ++j) r[j] = s[PAD(b1 + j)];
    fwht32_reg(r);
    #pragma unroll
    for (int j = 0; j < 32; ++j) s[PAD(b1 + j)] = r[j];
    __syncthreads();
    int b2 = (tid & 31) + (tid >> 5) * 1024; // pass 2: bits 5-9
    #pragma unroll
    for (int j = 0; j < 32; ++j) r[j] = s[PAD(b2 + 32 * j)];
    fwht32_reg(r);
    #pragma unroll
    for (int j = 0; j < 32; ++j) s[PAD(b2 + 32 * j)] = r[j];
    __syncthreads();
    #pragma unroll
    for (int jj = 0; jj < 4; ++jj) {         // pass 3: bits 10-12
        float g[8];
        int b3 = tid * 4 + jj;
        #pragma unroll
        for (int k = 0; k < 8; ++k) g[k] = s[PAD(b3 + 1024 * k)];
        #pragma unroll
        for (int h = 1; h < 8; h <<= 1)
            #pragma unroll
            for (int i = 0; i < 8; i += 2 * h)
                #pragma unroll
                for (int j = 0; j < h; ++j) {
                    float a = g[i + j], b = g[i + j + h];
                    g[i + j] = a + b;
                    g[i + j + h] = a - b;
                }
        #pragma unroll
        for (int k = 0; k < 8; ++k) s[PAD(b3 + 1024 * k)] = g[k];
    }
    __syncthreads();
}

// ---------------- kernel 1: codebook cvt + input FWHT ----------------
__global__ __launch_bounds__(256)
void prep_kernel(const float* __restrict__ cb, __bf16* __restrict__ cbb,
                 const float* __restrict__ x, const float* __restrict__ su,
                 __bf16* __restrict__ xh) {
    __shared__ float s[8192 + 256];
    const int tid = threadIdx.x;
    if (blockIdx.x < 512) {
        int i = blockIdx.x * 256 + tid;
        float4 v = ((const float4*)cb)[i];
        bf16x4 o;
        o[0] = (__bf16)v.x; o[1] = (__bf16)v.y;
        o[2] = (__bf16)v.z; o[3] = (__bf16)v.w;
        ((bf16x4*)cbb)[i] = o;
        return;
    }
    const int t = blockIdx.x - 512;
    #pragma unroll
    for (int i = tid; i < IN_F; i += 256)
        s[PAD(i)] = x[t * IN_F + i] * su[i];
    __syncthreads();
    fwht8192_lds(s, tid);
    #pragma unroll
    for (int i = tid; i < IN_F; i += 256)
        xh[t * IN_F + i] = (__bf16)(s[PAD(i)] * INV_SQRT_8192);
}

// ------ kernel 2: zpart = xh @ W^T (coalesced idx staging via LDS) --------
__global__ __launch_bounds__(512, 4)
void qgemm_kernel(const int* __restrict__ qidxs,
                  const __bf16* __restrict__ cb,
                  const __bf16* __restrict__ xh,
                  __bf16* __restrict__ zpart) {
    __shared__ __align__(16) __bf16 xt[TOKENS * XTK];   // 32 KB
    __shared__ __align__(16) int qs[2][8][512];         // 32 KB (buf,wave,int)
    const int ks = blockIdx.x & (KSPLIT - 1);
    const int nb = blockIdx.x >> 3;
    const int tid = threadIdx.x;
    const int wave = tid >> 6, lane = tid & 63;
    const int h = lane >> 5, lc = lane & 31;
    const int n0 = nb * 256 + wave * 32;
    const int n = n0 + lc;

    // xt half-stage (h2=0/1): 32 tok x 512 k, 16B chunks xor-swizzled
    auto stage_xt = [&](int h2) {
        #pragma unroll
        for (int i = 0; i < 4; ++i) {
            int f = i * 512 + tid, r = f >> 6, c = f & 63;
            i32x4 v = *(const i32x4*)(xh + (size_t)r * IN_F +
                                      ks * KCHUNK + h2 * XTK + c * 8);
            *(i32x4*)(xt + ((r * CH + (c ^ (r & 7))) << 3)) = v;
        }
    };

    // qidx chunk c = groups [4c,4c+4): 32 rows x 16 ints, 2KB/wave.
    // Load: fully coalesced (4 lanes x 16B = one 64B line per row-slice).
    auto LOADC = [&](int c, i32x4* lv) {
        #pragma unroll
        for (int i = 0; i < 2; ++i) {
            int slot = i * 64 + lane, row = slot >> 2, sp = slot & 3;
            lv[i] = *(const i32x4*)(qidxs + (size_t)(n0 + row) * (IN_F / 8)
                                    + ks * (KCHUNK / 8) + c * 16 + sp * 4);
        }
    };
    // Write: slot-swizzled (sp ^ row&3) so the per-lane read spreads banks.
    // sched_barrier keeps the compiler from hoisting the overwrite above the
    // last LDS read of the chunk that shared this buffer (WAR hazard).
    auto WRITEC = [&](int c, const i32x4* lv) {
        __builtin_amdgcn_sched_barrier(0);
        #pragma unroll
        for (int i = 0; i < 2; ++i) {
            int slot = i * 64 + lane, row = slot >> 2, sp = slot & 3;
            *(i32x4*)&qs[c & 1][wave][row * 16 + ((sp ^ (row & 3)) << 2)] =
                lv[i];
        }
    };
    #define IVRD(g) (*(const i32x4*)&qs[((g) >> 2) & 1][wave] \
                        [lc * 16 + ((((g) & 3) ^ (lc & 3)) << 2)])

#if HAVE_BUF
    // SRD over the bf16 codebook (1 MB). aux=1 -> SC0: L1-bypass, L2-cached.
    __amdgpu_buffer_rsrc_t rsrc = __builtin_amdgcn_make_buffer_rsrc(
        (void*)cb, (short)0, 65536 * 16, 0x00020000);
    #define GA(ix, au) __builtin_bit_cast(bf16x8, \
        __builtin_amdgcn_raw_buffer_load_b128(rsrc, (ix) << 4, 0, au))
#else
    const bf16x8* cbv = (const bf16x8*)cb;
    #define GA(ix, au) (cbv[ix])
#endif

    i32x4 rA[2], rB[2];
    LOADC(0, rA); LOADC(1, rB);
    stage_xt(0);
    WRITEC(0, rA); WRITEC(1, rB);
    __syncthreads();    // xt(half0) + own-wave qidx chunks 0,1 ready
    LOADC(2, rA); LOADC(3, rB);

    f32x16 acc;
    #pragma unroll
    for (int i = 0; i < 16; ++i) acc[i] = 0.f;

    i32x4 iv[GROUPS];
    bf16x8 bfr[GROUPS][2];

    #pragma unroll
    for (int g = 0; g < DI; ++g)
        iv[g] = IVRD(g);
    #pragma unroll
    for (int g = 0; g < DG; ++g) {
        if (g & 1) {
            bfr[g][0] = GA(h ? iv[g][1] : iv[g][0], 1);
            bfr[g][1] = GA(h ? iv[g][3] : iv[g][2], 1);
        } else {
            bfr[g][0] = GA(h ? iv[g][1] : iv[g][0], 0);
            bfr[g][1] = GA(h ? iv[g][3] : iv[g][2], 0);
        }
    }
    WRITEC(2, rA);      // chunk0 fully consumed in iv prologue
    LOADC(4, rA);

    #pragma unroll
    for (int g = 0; g < GROUPS; ++g) {
        // self-paced per-wave qidx staging: write chunk c=(g>>2)+3 at
        // g=1,5,9,13,17 (buffer-sharing chunk c-2 was last read at g-1)
        if ((g & 3) == 1 && g <= 17) {
            const int c = (g >> 2) + 3;
            if (c & 1) { WRITEC(c, rB); if (c + 2 <= 7) LOADC(c + 2, rB); }
            else       { WRITEC(c, rA); if (c + 2 <= 7) LOADC(c + 2, rA); }
        }
        if (g == 16) {               // swap xt to k-half 1
            __syncthreads();
            stage_xt(1);
            __syncthreads();
        }
        if (g + DI < GROUPS)
            iv[g + DI] = IVRD(g + DI);
        if (g + DG < GROUPS) {
            if ((g + DG) & 1) {
                bfr[g + DG][0] = GA(h ? iv[g + DG][1] : iv[g + DG][0], 1);
                bfr[g + DG][1] = GA(h ? iv[g + DG][3] : iv[g + DG][2], 1);
            } else {
                bfr[g + DG][0] = GA(h ? iv[g + DG][1] : iv[g + DG][0], 0);
                bfr[g + DG][1] = GA(h ? iv[g + DG][3] : iv[g + DG][2], 0);
            }
        }
        #pragma unroll
        for (int sgi = 0; sgi < 2; ++sgi) {
            const int T = 2 * (g & 15) + sgi;
            bf16x8 a = *(const bf16x8*)(xt +
                          ((lc * CH + ((2 * T + h) ^ (lc & 7))) << 3));
            acc = __builtin_amdgcn_mfma_f32_32x32x16_bf16(a, bfr[g][sgi],
                                                          acc, 0, 0, 0);
        }
    }

    // D[m=(r&3)+4h+8(r>>2)][n=lc] -> bf16 partials
    __bf16* zp = zpart + ((size_t)ks * TOKENS) * OUT_F + n;
    #pragma unroll
    for (int r = 0; r < 16; ++r) {
        int m = (r & 3) + 4 * h + 8 * (r >> 2);
        zp[(size_t)m * OUT_F] = (__bf16)acc[r];
    }
}

// ------- kernel 3: out = fwht(sum_ks zpart)/sqrt(n) * SV * Wscale ----------
__global__ __launch_bounds__(256)
void zsum_kernel(const __bf16* __restrict__ zpart, const float* __restrict__ sv,
                 const float* __restrict__ wscale, float* __restrict__ out) {
    __shared__ float s[8192 + 256];
    const int t = blockIdx.x, tid = threadIdx.x;
    #pragma unroll
    for (int cc = 0; cc < 4; ++cc) {
        int col = cc * 2048 + tid * 8;
        float a[8] = {0.f, 0.f, 0.f, 0.f, 0.f, 0.f, 0.f, 0.f};
        #pragma unroll
        for (int ks = 0; ks < KSPLIT; ++ks) {
            bf16x8 v = *(const bf16x8*)(zpart +
                         ((size_t)(ks * TOKENS + t)) * OUT_F + col);
            #pragma unroll
            for (int j = 0; j < 8; ++j) a[j] += (float)v[j];
        }
        #pragma unroll
        for (int j = 0; j < 8; ++j) s[PAD(col + j)] = a[j];
    }
    __syncthreads();
    fwht8192_lds(s, tid);
    const float sc = INV_SQRT_8192 * wscale[0];
    #pragma unroll
    for (int i = tid; i < OUT_F; i += 256)
        out[t * OUT_F + i] = s[PAD(i)] * sc * sv[i];
}

extern "C" void kernel_launch(void* const* d_in, const int* in_sizes, int n_in,
                              void* d_out, int out_size, void* d_ws, size_t ws_size,
                              hipStream_t stream) {
    const float* x      = (const float*)d_in[0];   // (32, 8192)
    const float* cb     = (const float*)d_in[1];   // (65536, 8)
    const int*   qidxs  = (const int*)d_in[2];     // (8192, 1024)
    const float* su     = (const float*)d_in[3];   // (8192,)
    const float* sv     = (const float*)d_in[4];   // (8192,)
    const float* wscale = (const float*)d_in[5];   // scalar
    float* out = (float*)d_out;                    // (32, 8192) fp32

    char* ws = (char*)d_ws;
    __bf16* cb_bf16 = (__bf16*)ws;                               // 1 MB
    __bf16* xh      = (__bf16*)(ws + (1u << 20));                // 512 KB
    __bf16* zpart   = (__bf16*)(ws + (1u << 20) + (512u << 10)); // 4 MB bf16

    hipLaunchKernelGGL(prep_kernel, dim3(544), dim3(256), 0, stream,
                       cb, cb_bf16, x, su, xh);
    hipLaunchKernelGGL(qgemm_kernel, dim3(32 * KSPLIT), dim3(512), 0, stream,
                       qidxs, cb_bf16, xh, zpart);
    hipLaunchKernelGGL(zsum_kernel, dim3(TOKENS), dim3(256), 0, stream,
                       zpart, sv, wscale, out);
}

// Round 3
// 127.784 us; speedup vs baseline: 1.0778x; 1.0778x over previous
//
#include <hip/hip_runtime.h>
#include <hip/hip_bf16.h>

// QuIP#-style quantized linear. R13: qgemm reverted verbatim to the R11
// champion (45.5us; R12's idx-staging regressed it). Seven structural nulls
// (occupancy x2.2, depth x4, L1/sc0/mixed, KSPLIT, idx-coalescing) pin
// qgemm at the per-CU gather-concurrency wall: 32768 random 16B gathers/CU
// x ~220cy L2 latency / ~64 outstanding ~= 46us. Irreducible.
// NEW: prep/zsum FWHTs re-factored for parallelism. H_8192 = H_8 (x) H_1024
// (bit-butterflies commute), so each FWHT splits into:
//   (a) strided FWHT-8 over bits 10-12: 32768 independent column tasks,
//       fully coalesced, 128 blocks;
//   (b) FWHT-1024 over bits 0-9: radix-4 LDS passes, 256 blocks
//       (32 tok x 8 chunks), all 256 threads active every stage.
// vs the old 32-block whole-token FWHT (12.5% of CUs, serial LDS chains).
// Diagnostic: qgemm unchanged -> any total delta isolates the ~88us
// residual (prep+zsum+overhead). If total stays ~130, residual is harness
// overhead and the gather wall is the structural ceiling.

typedef __attribute__((ext_vector_type(16))) float f32x16;
typedef __attribute__((ext_vector_type(8))) __bf16 bf16x8;
typedef __attribute__((ext_vector_type(4))) __bf16 bf16x4;
typedef __attribute__((ext_vector_type(4))) int i32x4;

#define IN_F 8192
#define OUT_F 8192
#define TOKENS 32
#define KSPLIT 8
#define KCHUNK 1024
#define CH (KCHUNK / 8)            // 128 16B-chunks per token row in LDS
#define GROUPS (KCHUNK / 32)       // 32 pipeline groups (4 codes each)
#define DG 5                       // gather lookahead (groups)
#define DI 7                       // idx lookahead (groups)
#define INV_SQRT_8192 0.011048543456039806f
#define PAD(i) ((i) + ((i) >> 5))

#if __has_builtin(__builtin_amdgcn_raw_buffer_load_b128) && \
    __has_builtin(__builtin_amdgcn_make_buffer_rsrc)
#define HAVE_BUF 1
#else
#define HAVE_BUF 0
#endif

// ---------------- register FWHT-8 (strided bits, order-free) --------------
__device__ inline void fwht8_reg(float* v) {
    #pragma unroll
    for (int h = 1; h < 8; h <<= 1)
        #pragma unroll
        for (int i = 0; i < 8; i += 2 * h)
            #pragma unroll
            for (int j = 0; j < h; ++j) {
                float a = v[i + j], b = v[i + j + h];
                v[i + j] = a + b;
                v[i + j + h] = a - b;
            }
}

// ---- FWHT-1024 (bits 0-9), 256 threads, radix-4, 5 stages --------------
// entry: v[j] = element 4*tid+j. exit: v[j] = element tid + j*256.
__device__ inline void fwht1024(float v[4], float* st, int tid) {
    {   // stage 0 (bits 0-1) in registers
        float t0 = v[0] + v[1], t1 = v[0] - v[1];
        float t2 = v[2] + v[3], t3 = v[2] - v[3];
        v[0] = t0 + t2; v[1] = t1 + t3; v[2] = t0 - t2; v[3] = t1 - t3;
    }
    int pos[4] = {4 * tid, 4 * tid + 1, 4 * tid + 2, 4 * tid + 3};
    #pragma unroll
    for (int s = 1; s < 5; ++s) {
        #pragma unroll
        for (int j = 0; j < 4; ++j) st[PAD(pos[j])] = v[j];
        __syncthreads();
        const int q = 1 << (2 * s);
        const int i = ((tid >> (2 * s)) << (2 * s + 2)) + (tid & (q - 1));
        #pragma unroll
        for (int j = 0; j < 4; ++j) { pos[j] = i + j * q; v[j] = st[PAD(pos[j])]; }
        __syncthreads();   // protect next stage's writes (WAR)
        float t0 = v[0] + v[1], t1 = v[0] - v[1];
        float t2 = v[2] + v[3], t3 = v[2] - v[3];
        v[0] = t0 + t2; v[1] = t1 + t3; v[2] = t0 - t2; v[3] = t1 - t3;
    }
}

// ---- prep A: xw[t,k*1024+c] = FWHT8_k( x[t,k*1024+c] * su[k*1024+c] ) ----
__global__ __launch_bounds__(256)
void prepA_kernel(const float* __restrict__ x, const float* __restrict__ su,
                  float* __restrict__ xw) {
    const int id = blockIdx.x * 256 + threadIdx.x;   // 32768 tasks
    const int t = id >> 10, c = id & 1023;
    float v[8];
    #pragma unroll
    for (int k = 0; k < 8; ++k)
        v[k] = x[t * IN_F + k * 1024 + c] * su[k * 1024 + c];
    fwht8_reg(v);
    #pragma unroll
    for (int k = 0; k < 8; ++k)
        xw[t * IN_F + k * 1024 + c] = v[k];
}

// ---- prep B: codebook cvt (blocks <512) + FWHT-1024 + bf16 cvt ----------
__global__ __launch_bounds__(256)
void prepB_kernel(const float* __restrict__ cb, __bf16* __restrict__ cbb,
                  const float* __restrict__ xw, __bf16* __restrict__ xh) {
    __shared__ float st[1056];
    const int tid = threadIdx.x;
    if (blockIdx.x < 512) {
        int i = blockIdx.x * 256 + tid;
        float4 vv = ((const float4*)cb)[i];
        bf16x4 o;
        o[0] = (__bf16)vv.x; o[1] = (__bf16)vv.y;
        o[2] = (__bf16)vv.z; o[3] = (__bf16)vv.w;
        ((bf16x4*)cbb)[i] = o;
        return;
    }
    const int id = blockIdx.x - 512;                 // 256 tasks
    const int t = id >> 3, ch = id & 7;
    const float* src = xw + (size_t)t * IN_F + ch * 1024;
    float4 f = ((const float4*)src)[tid];
    float v[4] = {f.x, f.y, f.z, f.w};
    fwht1024(v, st, tid);
    __bf16* dst = xh + (size_t)t * IN_F + ch * 1024;
    #pragma unroll
    for (int j = 0; j < 4; ++j)
        dst[tid + j * 256] = (__bf16)(v[j] * INV_SQRT_8192);
}

// ---------------- kernel 2: zpart = xh @ W^T (R11 champion, verbatim) -----
__global__ __launch_bounds__(512, 4)
void qgemm_kernel(const int* __restrict__ qidxs,
                  const __bf16* __restrict__ cb,
                  const __bf16* __restrict__ xh,
                  __bf16* __restrict__ zpart) {
    __shared__ __align__(16) __bf16 xt[TOKENS * KCHUNK];   // 64 KB
    const int ks = blockIdx.x & (KSPLIT - 1);
    const int nb = blockIdx.x >> 3;
    const int tid = threadIdx.x;
    const int wave = tid >> 6, lane = tid & 63;
    const int h = lane >> 5, lc = lane & 31;
    const int n = nb * 256 + wave * 32 + lc;

    // stage xh k-slice (32 tok x 1024 k) -> LDS, 16B chunks xor-swizzled
    #pragma unroll
    for (int i = 0; i < 8; ++i) {
        int f = i * 512 + tid, r = f >> 7, c = f & 127;
        i32x4 v = *(const i32x4*)(xh + (size_t)r * IN_F + ks * KCHUNK + c * 8);
        *(i32x4*)(xt + ((r * CH + (c ^ (r & 7))) << 3)) = v;
    }
    __syncthreads();    // the only barrier

    const int* qrow = qidxs + (size_t)n * (IN_F / 8) + ks * (KCHUNK / 8);

#if HAVE_BUF
    // SRD over the bf16 codebook (1 MB). aux=1 -> SC0: L1-bypass, L2-cached.
    __amdgpu_buffer_rsrc_t rsrc = __builtin_amdgcn_make_buffer_rsrc(
        (void*)cb, (short)0, 65536 * 16, 0x00020000);
    #define GA(ix, au) __builtin_bit_cast(bf16x8, \
        __builtin_amdgcn_raw_buffer_load_b128(rsrc, (ix) << 4, 0, au))
#else
    const bf16x8* cbv = (const bf16x8*)cb;
    #define GA(ix, au) (cbv[ix])
#endif

    f32x16 acc;
    #pragma unroll
    for (int i = 0; i < 16; ++i) acc[i] = 0.f;

    i32x4 iv[GROUPS];
    bf16x8 bfr[GROUPS][2];

    #pragma unroll
    for (int g = 0; g < DI; ++g)
        iv[g] = *(const i32x4*)(qrow + g * 4);
    #pragma unroll
    for (int g = 0; g < DG; ++g) {
        if (g & 1) {
            bfr[g][0] = GA(h ? iv[g][1] : iv[g][0], 1);
            bfr[g][1] = GA(h ? iv[g][3] : iv[g][2], 1);
        } else {
            bfr[g][0] = GA(h ? iv[g][1] : iv[g][0], 0);
            bfr[g][1] = GA(h ? iv[g][3] : iv[g][2], 0);
        }
    }

    #pragma unroll
    for (int g = 0; g < GROUPS; ++g) {
        if (g + DI < GROUPS)
            iv[g + DI] = *(const i32x4*)(qrow + (g + DI) * 4);
        if (g + DG < GROUPS) {
            if ((g + DG) & 1) {
                bfr[g + DG][0] = GA(h ? iv[g + DG][1] : iv[g + DG][0], 1);
                bfr[g + DG][1] = GA(h ? iv[g + DG][3] : iv[g + DG][2], 1);
            } else {
                bfr[g + DG][0] = GA(h ? iv[g + DG][1] : iv[g + DG][0], 0);
                bfr[g + DG][1] = GA(h ? iv[g + DG][3] : iv[g + DG][2], 0);
            }
        }
        #pragma unroll
        for (int sgi = 0; sgi < 2; ++sgi) {
            const int T = 2 * g + sgi;
            bf16x8 a = *(const bf16x8*)(xt +
                          ((lc * CH + ((2 * T + h) ^ (lc & 7))) << 3));
            acc = __builtin_amdgcn_mfma_f32_32x32x16_bf16(a, bfr[g][sgi],
                                                          acc, 0, 0, 0);
        }
    }

    // D[m=(r&3)+4h+8(r>>2)][n=lc] -> bf16 partials
    __bf16* zp = zpart + ((size_t)ks * TOKENS) * OUT_F + n;
    #pragma unroll
    for (int r = 0; r < 16; ++r) {
        int m = (r & 3) + 4 * h + 8 * (r >> 2);
        zp[(size_t)m * OUT_F] = (__bf16)acc[r];
    }
}

// ---- zsum A: z1[t,ch*1024+:] = FWHT1024( sum_ks zpart ) ------------------
__global__ __launch_bounds__(256)
void zsumA_kernel(const __bf16* __restrict__ zpart, float* __restrict__ z1) {
    __shared__ float st[1056];
    const int tid = threadIdx.x;
    const int t = blockIdx.x >> 3, ch = blockIdx.x & 7;  // 256 blocks
    float v[4] = {0.f, 0.f, 0.f, 0.f};
    #pragma unroll
    for (int ks = 0; ks < KSPLIT; ++ks) {
        bf16x4 b = *(const bf16x4*)(zpart +
                     ((size_t)(ks * TOKENS + t)) * OUT_F + ch * 1024 + tid * 4);
        v[0] += (float)b[0]; v[1] += (float)b[1];
        v[2] += (float)b[2]; v[3] += (float)b[3];
    }
    fwht1024(v, st, tid);
    float* dst = z1 + (size_t)t * OUT_F + ch * 1024;
    #pragma unroll
    for (int j = 0; j < 4; ++j)
        dst[tid + j * 256] = v[j];
}

// ---- zsum B: out = FWHT8(bits 10-12 of z1) * scale * sv ------------------
__global__ __launch_bounds__(256)
void zsumB_kernel(const float* __restrict__ z1, const float* __restrict__ sv,
                  const float* __restrict__ wscale, float* __restrict__ out) {
    const int id = blockIdx.x * 256 + threadIdx.x;   // 32768 tasks
    const int t = id >> 10, c = id & 1023;
    float v[8];
    #pragma unroll
    for (int k = 0; k < 8; ++k)
        v[k] = z1[t * OUT_F + k * 1024 + c];
    fwht8_reg(v);
    const float sc = INV_SQRT_8192 * wscale[0];
    #pragma unroll
    for (int k = 0; k < 8; ++k)
        out[t * OUT_F + k * 1024 + c] = v[k] * sc * sv[k * 1024 + c];
}

extern "C" void kernel_launch(void* const* d_in, const int* in_sizes, int n_in,
                              void* d_out, int out_size, void* d_ws, size_t ws_size,
                              hipStream_t stream) {
    const float* x      = (const float*)d_in[0];   // (32, 8192)
    const float* cb     = (const float*)d_in[1];   // (65536, 8)
    const int*   qidxs  = (const int*)d_in[2];     // (8192, 1024)
    const float* su     = (const float*)d_in[3];   // (8192,)
    const float* sv     = (const float*)d_in[4];   // (8192,)
    const float* wscale = (const float*)d_in[5];   // scalar
    float* out = (float*)d_out;                    // (32, 8192) fp32

    char* ws = (char*)d_ws;
    __bf16* cb_bf16 = (__bf16*)ws;                               // 1 MB
    __bf16* xh      = (__bf16*)(ws + (1u << 20));                // 512 KB
    __bf16* zpart   = (__bf16*)(ws + (1u << 20) + (512u << 10)); // 4 MB bf16
    float*  xw      = (float*)(ws + (5u << 20) + (512u << 10));  // 1 MB fp32
    float*  z1      = (float*)(ws + (6u << 20) + (512u << 10));  // 1 MB fp32

    hipLaunchKernelGGL(prepA_kernel, dim3(128), dim3(256), 0, stream,
                       x, su, xw);
    hipLaunchKernelGGL(prepB_kernel, dim3(768), dim3(256), 0, stream,
                       cb, cb_bf16, xw, xh);
    hipLaunchKernelGGL(qgemm_kernel, dim3(32 * KSPLIT), dim3(512), 0, stream,
                       qidxs, cb_bf16, xh, zpart);
    hipLaunchKernelGGL(zsumA_kernel, dim3(256), dim3(256), 0, stream,
                       zpart, z1);
    hipLaunchKernelGGL(zsumB_kernel, dim3(128), dim3(256), 0, stream,
                       z1, sv, wscale, out);
}